// Round 19
// baseline (1023.512 us; speedup 1.0000x reference)
//
#include <hip/hip_runtime.h>
#include <hip/hip_bf16.h>
#include <math.h>

#define LSEQ 2048
#define NM   64     // N modes
#define HD   64     // H
#define NDIV 8
#define NB   8      // batch
#define NF   2049   // rfft bins of 4096
#define NFP  2052   // padded row stride for big/kdt (16B-aligned rows)
#define ATROWS 4224 // 4096 ij + 64 Mp + 64 Mq

// XOR-swizzled LDS slot: bijective involution on [0,2048); all radix-8/4
// access families land 4 lanes per bank-pair (b64 conflict-free minimum).
#define SL(E) ((E) ^ (((E) >> 4) & 15))
#define FFT_BUF 2048

typedef __attribute__((ext_vector_type(8))) short bf16x8;
typedef __attribute__((ext_vector_type(4))) float f32x4;

// ---------------- bf16 helpers ----------------
__device__ __forceinline__ unsigned pack_c(float2 v) {
  __hip_bfloat162 h = __float22bfloat162_rn(v);
  return *reinterpret_cast<unsigned*>(&h);
}
__device__ __forceinline__ float2 unpack_c(unsigned u) {
  __hip_bfloat162 h = *reinterpret_cast<__hip_bfloat162*>(&u);
  return __bfloat1622float2(h);
}
__device__ __forceinline__ unsigned short f2bf(float v) {
  __hip_bfloat16 h = __float2bfloat16(v);
  return *reinterpret_cast<unsigned short*>(&h);
}

// ---------------- complex helpers ----------------
__device__ __forceinline__ float2 cadd(float2 a, float2 b) { return make_float2(a.x+b.x, a.y+b.y); }
__device__ __forceinline__ float2 csub(float2 a, float2 b) { return make_float2(a.x-b.x, a.y-b.y); }
__device__ __forceinline__ float2 cmulf(float2 a, float2 b) {
  return make_float2(a.x*b.x - a.y*b.y, a.x*b.y + a.y*b.x);
}

struct cplxd { double x, y; };
__device__ __forceinline__ cplxd cmuld(cplxd a, cplxd b) {
  return {a.x*b.x - a.y*b.y, a.x*b.y + a.y*b.x};
}
__device__ __forceinline__ cplxd cdivd(cplxd a, cplxd b) {
  double inv = 1.0 / (b.x*b.x + b.y*b.y);
  return {(a.x*b.x + a.y*b.y)*inv, (a.y*b.x - a.x*b.y)*inv};
}

// ---------------- 8-point DFT in registers (a[0..7] in/out) ----------------
template<int SIGN>
__device__ __forceinline__ void dft8(float2* a) {
  const float R = 0.70710678118654752f;
  float2 e0 = cadd(a[0], a[4]), e1 = cadd(a[2], a[6]);
  float2 d0 = csub(a[0], a[4]), d1 = csub(a[2], a[6]);
  float2 t0 = cadd(e0, e1), t2 = csub(e0, e1);
  float2 t1, t3;
  if (SIGN < 0) { t1 = make_float2(d0.x + d1.y, d0.y - d1.x);
                  t3 = make_float2(d0.x - d1.y, d0.y + d1.x); }
  else          { t1 = make_float2(d0.x - d1.y, d0.y + d1.x);
                  t3 = make_float2(d0.x + d1.y, d0.y - d1.x); }
  float2 f0 = cadd(a[1], a[5]), f1 = cadd(a[3], a[7]);
  float2 g0 = csub(a[1], a[5]), g1 = csub(a[3], a[7]);
  float2 s0 = cadd(f0, f1), s2 = csub(f0, f1);
  float2 s1, s3;
  if (SIGN < 0) { s1 = make_float2(g0.x + g1.y, g0.y - g1.x);
                  s3 = make_float2(g0.x - g1.y, g0.y + g1.x); }
  else          { s1 = make_float2(g0.x - g1.y, g0.y + g1.x);
                  s3 = make_float2(g0.x + g1.y, g0.y - g1.x); }
  float2 r1, r2, r3;
  if (SIGN < 0) {
    r1 = make_float2(R*(s1.x + s1.y), R*(s1.y - s1.x));
    r2 = make_float2(s2.y, -s2.x);
    r3 = make_float2(R*(s3.y - s3.x), -R*(s3.x + s3.y));
  } else {
    r1 = make_float2(R*(s1.x - s1.y), R*(s1.x + s1.y));
    r2 = make_float2(-s2.y, s2.x);
    r3 = make_float2(-R*(s3.x + s3.y), R*(s3.x - s3.y));
  }
  a[0] = cadd(t0, s0); a[4] = csub(t0, s0);
  a[1] = cadd(t1, r1); a[5] = csub(t1, r1);
  a[2] = cadd(t2, r2); a[6] = csub(t2, r2);
  a[3] = cadd(t3, r3); a[7] = csub(t3, r3);
}

// ---------------- in-place Stockham radix-8 stage; read/write barriers ----------------
template<int SIGN, int M>
__device__ __forceinline__ void r8_ip(float2* __restrict__ bb) {
  __syncthreads();                     // prior stage's writes visible
  int idx = (int)threadIdx.x;          // [0,256)
  int q = idx / M, p = idx - q*M;
  float2 a[8];
  #pragma unroll
  for (int v = 0; v < 8; v++) a[v] = bb[SL(idx + 256*v)];
  if constexpr (M > 1) {
    float s, c;
    __sincosf(-6.28318530717958647f * (float)p / (8.0f * (float)M), &s, &c);
    if (SIGN > 0) s = -s;
    float2 W1 = make_float2(c, s);
    float2 W2 = cmulf(W1, W1);
    float2 W3 = cmulf(W2, W1);
    float2 W4 = cmulf(W2, W2);
    float2 W5 = cmulf(W3, W2);
    float2 W6 = cmulf(W3, W3);
    float2 W7 = cmulf(W4, W3);
    a[1] = cmulf(a[1], W1); a[2] = cmulf(a[2], W2); a[3] = cmulf(a[3], W3);
    a[4] = cmulf(a[4], W4); a[5] = cmulf(a[5], W5); a[6] = cmulf(a[6], W6);
    a[7] = cmulf(a[7], W7);
  }
  dft8<SIGN>(a);
  __syncthreads();                     // all reads complete before overwrite
  int ob = q * 8 * M + p;
  #pragma unroll
  for (int u = 0; u < 8; u++) bb[SL(ob + u*M)] = a[u];
}

// k2 FFT#1 stage 1 (SIGN=+1, M=1): reads bf16 row direct from global (no twiddle)
__device__ __forceinline__ void r8g_bf16_inv(const unsigned* __restrict__ row,
                                             float2* __restrict__ bb) {
  int idx = (int)threadIdx.x;
  float2 a[8];
  #pragma unroll
  for (int v = 0; v < 8; v++) a[v] = unpack_c(row[idx + 256*v]);
  dft8<1>(a);
  int ob = idx * 8;
  #pragma unroll
  for (int u = 0; u < 8; u++) bb[SL(ob + u)] = a[u];
}

// k3 stage 1 (SIGN=-1, M=1): reads f32 z-pairs from global, upper half zero
__device__ __forceinline__ void r8g_f32pad_fwd(const float2* __restrict__ g,
                                               float2* __restrict__ bb) {
  int idx = (int)threadIdx.x;
  float2 a[8];
  #pragma unroll
  for (int v = 0; v < 4; v++) a[v] = g[idx + 256*v];
  #pragma unroll
  for (int v = 4; v < 8; v++) a[v] = make_float2(0.f, 0.f);
  dft8<-1>(a);
  int ob = idx * 8;
  #pragma unroll
  for (int u = 0; u < 8; u++) bb[SL(ob + u)] = a[u];
}

// final radix-4 (M=512) in-place, full output (per-thread same-slot: 1 barrier)
template<int SIGN>
__device__ __forceinline__ void r4f_ip(float2* __restrict__ bb) {
  __syncthreads();
  #pragma unroll
  for (int t = 0; t < 2; t++) {
    int p = (int)threadIdx.x + t * 256;
    float2 a0 = bb[SL(p)], a1 = bb[SL(p + 512)];
    float2 a2 = bb[SL(p + 1024)], a3 = bb[SL(p + 1536)];
    float s, c;
    __sincosf(-6.28318530717958647f * (float)p * (1.0f/2048.0f), &s, &c);
    if (SIGN > 0) s = -s;
    float2 W1 = make_float2(c, s);
    float2 W2 = cmulf(W1, W1);
    float2 W3 = cmulf(W2, W1);
    float2 b1 = cmulf(a1, W1), b2 = cmulf(a2, W2), b3 = cmulf(a3, W3);
    float2 e0 = cadd(a0, b2), e1 = cadd(b1, b3);
    float2 d0 = csub(a0, b2), d1 = csub(b1, b3);
    float2 o1, o3;
    if (SIGN < 0) { o1 = make_float2(d0.x + d1.y, d0.y - d1.x);
                    o3 = make_float2(d0.x - d1.y, d0.y + d1.x); }
    else          { o1 = make_float2(d0.x - d1.y, d0.y + d1.x);
                    o3 = make_float2(d0.x + d1.y, d0.y - d1.x); }
    bb[SL(p)]        = cadd(e0, e1);
    bb[SL(p + 512)]  = o1;
    bb[SL(p + 1024)] = csub(e0, e1);
    bb[SL(p + 1536)] = o3;
  }
}

// k2: final r4 of the INVERSE fft fused with Re()*(1/2048)*mod (in-place)
__device__ __forceinline__ void r4f_mod_ip(float2* __restrict__ bb) {
  __syncthreads();
  const float sc = 1.0f/2048.0f;
  const float R = 0.70710678118654752f;
  #pragma unroll
  for (int t = 0; t < 2; t++) {
    int p = (int)threadIdx.x + t * 256;
    float2 a0 = bb[SL(p)], a1 = bb[SL(p + 512)];
    float2 a2 = bb[SL(p + 1024)], a3 = bb[SL(p + 1536)];
    float s, c;
    __sincosf(-6.28318530717958647f * (float)p * (1.0f/2048.0f), &s, &c);
    float2 W1 = make_float2(c, -s);          // inverse twiddle
    float2 W2 = cmulf(W1, W1);
    float2 W3 = cmulf(W2, W1);
    float2 b1 = cmulf(a1, W1), b2 = cmulf(a2, W2), b3 = cmulf(a3, W3);
    float2 e0 = cadd(a0, b2), e1 = cadd(b1, b3);
    float2 d0 = csub(a0, b2), d1 = csub(b1, b3);
    float kr0 = (e0.x + e1.x) * sc;          // z[p]
    float kr1 = (d0.x - d1.y) * sc;          // z[p+512]
    float kr2 = (e0.x - e1.x) * sc;          // z[p+1024]
    float kr3 = (d0.x + d1.y) * sc;          // z[p+1536]
    float ms, mc;
    __sincosf(-3.14159265358979324f * (float)p * (1.0f/2048.0f), &ms, &mc);
    bb[SL(p)]        = make_float2(kr0*mc,           kr0*ms);
    bb[SL(p + 512)]  = make_float2(kr1*R*(mc + ms),  kr1*R*(ms - mc));
    bb[SL(p + 1024)] = make_float2(kr2*ms,          -kr2*mc);
    bb[SL(p + 1536)] = make_float2(kr3*R*(ms - mc), -kr3*R*(mc + ms));
  }
}

// k2 forward final r4 (SIGN=-1): write odd bins 2k+1 (k<1024 only) packed bf16
__device__ __forceinline__ void r4f_gw_bf16(const float2* __restrict__ bb,
                                            unsigned* __restrict__ row) {
  __syncthreads();
  #pragma unroll
  for (int t = 0; t < 2; t++) {
    int p = (int)threadIdx.x + t * 256;
    float2 a0 = bb[SL(p)], a1 = bb[SL(p + 512)];
    float2 a2 = bb[SL(p + 1024)], a3 = bb[SL(p + 1536)];
    float s, c;
    __sincosf(-6.28318530717958647f * (float)p * (1.0f/2048.0f), &s, &c);
    float2 W1 = make_float2(c, s);
    float2 W2 = cmulf(W1, W1);
    float2 W3 = cmulf(W2, W1);
    float2 b1 = cmulf(a1, W1), b2 = cmulf(a2, W2), b3 = cmulf(a3, W3);
    float2 e0 = cadd(a0, b2), e1 = cadd(b1, b3);
    float2 d0 = csub(a0, b2), d1 = csub(b1, b3);
    float2 z0 = cadd(e0, e1);                               // k = p
    float2 z1 = make_float2(d0.x + d1.y, d0.y - d1.x);      // k = p+512
    row[2*p + 1]       = pack_c(z0);
    row[2*(p+512) + 1] = pack_c(z1);
  }
}

// k5 final r4 (SIGN=+1): only t<1024 needed; scaled; writes f32 pairs to global
__device__ __forceinline__ void r4f_gw_f32h(const float2* __restrict__ bb,
                                            float2* __restrict__ dst) {
  __syncthreads();
  const float sc = 1.0f/2048.0f;
  #pragma unroll
  for (int t = 0; t < 2; t++) {
    int p = (int)threadIdx.x + t * 256;
    float2 a0 = bb[SL(p)], a1 = bb[SL(p + 512)];
    float2 a2 = bb[SL(p + 1024)], a3 = bb[SL(p + 1536)];
    float s, c;
    __sincosf(-6.28318530717958647f * (float)p * (1.0f/2048.0f), &s, &c);
    float2 W1 = make_float2(c, -s);          // inverse twiddle
    float2 W2 = cmulf(W1, W1);
    float2 W3 = cmulf(W2, W1);
    float2 b1 = cmulf(a1, W1), b2 = cmulf(a2, W2), b3 = cmulf(a3, W3);
    float2 e0 = cadd(a0, b2), e1 = cadd(b1, b3);
    float2 d0 = csub(a0, b2), d1 = csub(b1, b3);
    float2 z0 = cadd(e0, e1);
    float2 z1 = make_float2(d0.x - d1.y, d0.y + d1.x);
    dst[p]       = make_float2(z0.x*sc, z0.y*sc);
    dst[p + 512] = make_float2(z1.x*sc, z1.y*sc);
  }
}

// ---------------- KT: params -> div-major coalesced layouts ----------------
__global__ __launch_bounds__(256) void ssm_kt(
    const float* __restrict__ Cre, const float* __restrict__ Cim,
    const float* __restrict__ Bre, const float* __restrict__ Bim,
    const float* __restrict__ Pre, const float* __restrict__ Pim,
    float2* __restrict__ CT, float2* __restrict__ BT, float2* __restrict__ PT) {
  int idx = blockIdx.x * 256 + threadIdx.x;   // 32768 = dv*4096 + n*64 + x
  int dv = idx >> 12, n = (idx >> 6) & 63, x = idx & 63;
  CT[idx] = make_float2(Cre[((size_t)x*NM + n)*NDIV + dv], -Cim[((size_t)x*NM + n)*NDIV + dv]);
  BT[idx] = make_float2(Bre[((size_t)n*HD + x)*NDIV + dv],  Bim[((size_t)n*HD + x)*NDIV + dv]);
  if (idx < NDIV*NM) {
    int dv2 = idx >> 6, n2 = idx & 63;
    PT[idx] = make_float2(Pre[n2*NDIV + dv2], Pim[n2*NDIV + dv2]);
  }
}

// ---------------- K0a: rcb bf16 planes (k-interleaved) + cpx ----------------
__global__ __launch_bounds__(256) void ssm_k0a(
    const float* __restrict__ Lre, const float* __restrict__ Lim,
    const float* __restrict__ Pre, const float* __restrict__ Pim,
    const float* __restrict__ step, unsigned short* __restrict__ RBr,
    unsigned short* __restrict__ RBi, float2* __restrict__ cpx) {
  int idx = blockIdx.x * 256 + threadIdx.x;     // 65536 = (dv*2048 + l)*4 + qn
  int qn = idx & 3;
  int rest = idx >> 2;
  int l = rest & (LSEQ - 1);
  int dv = rest >> 11;
  double s = (double)expf(step[0]);
  float angf = -6.2831855f * ((float)l * (1.0f/2048.0f));
  double si, co;
  sincos((double)angf, &si, &co);
  cplxd om    = {co, si};
  cplxd one_p = {1.0 + om.x,  om.y};
  double ts = 2.0 / s;
  cplxd g = cdivd({ts*(1.0 - om.x), ts*(-om.y)}, one_p);
  cplxd c = cdivd({2.0, 0.0}, one_p);
  double k11x = 0.0, k11y = 0.0;
  for (int u = 0; u < 16; u++) {
    int n = qn*16 + u;
    float lre = fminf(Lre[n*NDIV+dv], -0.0001f);
    float lim = Lim[n*NDIV+dv];
    cplxd den = {g.x - (double)lre, g.y - (double)lim};
    cplxd r   = cdivd({1.0, 0.0}, den);
    cplxd rcv = cmuld(c, r);
    size_t bidx = (((size_t)(dv*8 + (n >> 3)))*LSEQ + l)*8 + (n & 7);
    RBr[bidx] = f2bf((float)rcv.x);
    RBi[bidx] = f2bf((float)rcv.y);
    double pr = (double)Pre[n*NDIV+dv], pi = (double)Pim[n*NDIV+dv];
    double p2 = pr*pr + pi*pi;                  // conj(p)*p is real
    k11x += p2 * rcv.x; k11y += p2 * rcv.y;
  }
  k11x += __shfl_xor(k11x, 1); k11y += __shfl_xor(k11y, 1);
  k11x += __shfl_xor(k11x, 2); k11y += __shfl_xor(k11y, 2);
  if (qn == 0)
    cpx[(size_t)dv*LSEQ + l] = make_float2((float)(c.x + k11x), (float)(c.y + k11y));
}

// ---------------- KM: build AT planes (rows: 4096 ij, 64 Mp, 64 Mq) ----------------
__global__ __launch_bounds__(256) void ssm_km(
    const float2* __restrict__ CT, const float2* __restrict__ BT,
    const float2* __restrict__ PT, unsigned short* __restrict__ ATr,
    unsigned short* __restrict__ ATi, unsigned short* __restrict__ ATin) {
  __shared__ float2 PAN[4096];   // 32 KB
  __shared__ float2 ROW[64];
  int dv = blockIdx.y;
  int ib = blockIdx.x;           // 0..63 = i; 64 = Mp/Mq block
  int tid = threadIdx.x;
  if (ib < 64) {
    for (int q = tid; q < 4096; q += 256) PAN[q] = BT[(size_t)dv*4096 + q];  // [n][j]
    if (tid < 64) ROW[tid] = CT[(size_t)dv*4096 + tid*64 + ib];              // CC[ib][n]
    __syncthreads();
    int j = tid >> 2, nq = tid & 3;
    size_t rbase = ((size_t)dv*ATROWS + ib*64 + j)*64;
    for (int u = 0; u < 16; u++) {
      int n = nq*16 + u;
      float2 cv = ROW[n];
      float2 bv = PAN[n*64 + j];
      float xr = cv.x*bv.x - cv.y*bv.y, xi = cv.x*bv.y + cv.y*bv.x;
      ATr[rbase + n] = f2bf(xr); ATi[rbase + n] = f2bf(xi); ATin[rbase + n] = f2bf(-xi);
    }
  } else {
    for (int q = tid; q < 4096; q += 256) PAN[q] = CT[(size_t)dv*4096 + q];  // [n][x]
    if (tid < 64) ROW[tid] = PT[dv*64 + tid];
    __syncthreads();
    int x = tid >> 2, nq = tid & 3;
    size_t pbase = ((size_t)dv*ATROWS + 4096 + x)*64;
    for (int u = 0; u < 16; u++) {
      int n = nq*16 + u;
      float2 cv = PAN[n*64 + x];
      float2 pv = ROW[n];
      float xr = cv.x*pv.x - cv.y*pv.y, xi = cv.x*pv.y + cv.y*pv.x;
      ATr[pbase + n] = f2bf(xr); ATi[pbase + n] = f2bf(xi); ATin[pbase + n] = f2bf(-xi);
    }
    __syncthreads();
    for (int q = tid; q < 4096; q += 256) PAN[q] = BT[(size_t)dv*4096 + q];
    __syncthreads();
    size_t qbase = ((size_t)dv*ATROWS + 4160 + x)*64;
    for (int u = 0; u < 16; u++) {
      int n = nq*16 + u;
      float2 bv = PAN[n*64 + x];
      float2 pv = ROW[n];
      float xr = pv.x*bv.x + pv.y*bv.y, xi = pv.x*bv.y - pv.y*bv.x;
      ATr[qbase + n] = f2bf(xr); ATi[qbase + n] = f2bf(xi); ATin[qbase + n] = f2bf(-xi);
    }
  }
}

// ---------------- MFMA GEMM core ----------------
__device__ __forceinline__ void gemm_core(
    const unsigned short* __restrict__ ATr, const unsigned short* __restrict__ ATi,
    const unsigned short* __restrict__ ATin, const unsigned short* __restrict__ RBr,
    const unsigned short* __restrict__ RBi, int dv, int mrow0, int l0, int lane,
    f32x4 accR[4], f32x4 accI[4]) {
  int mloc = lane & 15, kgrp = lane >> 4;
  #pragma unroll
  for (int t = 0; t < 4; t++) {
    accR[t] = (f32x4){0.f, 0.f, 0.f, 0.f};
    accI[t] = (f32x4){0.f, 0.f, 0.f, 0.f};
  }
  size_t abase = ((size_t)dv*ATROWS + mrow0 + mloc)*64 + kgrp*8;
  #pragma unroll
  for (int s = 0; s < 2; s++) {
    bf16x8 ar = *reinterpret_cast<const bf16x8*>(ATr  + abase + s*32);
    bf16x8 ai = *reinterpret_cast<const bf16x8*>(ATi  + abase + s*32);
    bf16x8 an = *reinterpret_cast<const bf16x8*>(ATin + abase + s*32);
    size_t bbase = (((size_t)(dv*8 + s*4 + kgrp))*LSEQ + l0 + mloc)*8;
    #pragma unroll
    for (int t = 0; t < 4; t++) {
      bf16x8 br = *reinterpret_cast<const bf16x8*>(RBr + bbase + t*128);
      bf16x8 bi = *reinterpret_cast<const bf16x8*>(RBi + bbase + t*128);
      accR[t] = __builtin_amdgcn_mfma_f32_16x16x32_bf16(ar, br, accR[t], 0, 0, 0);
      accR[t] = __builtin_amdgcn_mfma_f32_16x16x32_bf16(an, bi, accR[t], 0, 0, 0);
      accI[t] = __builtin_amdgcn_mfma_f32_16x16x32_bf16(ar, bi, accI[t], 0, 0, 0);
      accI[t] = __builtin_amdgcn_mfma_f32_16x16x32_bf16(ai, br, accI[t], 0, 0, 0);
    }
  }
}

// ---------------- G1: Woodbury vectors ----------------
__global__ __launch_bounds__(256) void ssm_g1(
    const unsigned short* __restrict__ ATr, const unsigned short* __restrict__ ATi,
    const unsigned short* __restrict__ ATin, const unsigned short* __restrict__ RBr,
    const unsigned short* __restrict__ RBi, const float2* __restrict__ cpx,
    float2* __restrict__ A1h, float2* __restrict__ K10h) {
  int which = blockIdx.x;          // 0 = Mp -> A1h, 1 = Mq -> K10h
  int nBlk = blockIdx.y;
  int dv = blockIdx.z;
  int wave = threadIdx.x >> 6, lane = threadIdx.x & 63;
  int mrow0 = 4096 + which*64 + wave*16;
  int l0 = nBlk * 64;
  f32x4 accR[4], accI[4];
  gemm_core(ATr, ATi, ATin, RBr, RBi, dv, mrow0, l0, lane, accR, accI);
  int rbase = (lane >> 4) * 4;
  #pragma unroll
  for (int t = 0; t < 4; t++) {
    int l = l0 + t*16 + (lane & 15);
    if (which == 0) {
      float2 w = cpx[((size_t)dv << 11) + l];
      float inv = 1.0f / (w.x*w.x + w.y*w.y);
      #pragma unroll
      for (int r = 0; r < 4; r++) {
        int x = wave*16 + rbase + r;
        float sx = accR[t][r], sy = accI[t][r];
        A1h[((size_t)(dv*64 + x))*LSEQ + l] =
            make_float2((sx*w.x + sy*w.y)*inv, (sy*w.x - sx*w.y)*inv);
      }
    } else {
      #pragma unroll
      for (int r = 0; r < 4; r++) {
        int x = wave*16 + rbase + r;
        K10h[((size_t)(dv*LSEQ + l))*64 + x] = make_float2(accR[t][r], accI[t][r]);
      }
    }
  }
}

// ---------------- G2: at_roots GEMM + rank-1 correction ----------------
__global__ __launch_bounds__(256) void ssm_g2(
    const unsigned short* __restrict__ ATr, const unsigned short* __restrict__ ATi,
    const unsigned short* __restrict__ ATin, const unsigned short* __restrict__ RBr,
    const unsigned short* __restrict__ RBi, const float2* __restrict__ A1h,
    const float2* __restrict__ K10h, unsigned* __restrict__ big, int dv) {
  int mBlk = blockIdx.x;           // = i
  int nBlk = blockIdx.y;
  int wave = threadIdx.x >> 6, lane = threadIdx.x & 63;
  int mrow0 = mBlk*64 + wave*16;
  int l0 = nBlk * 64;
  f32x4 accR[4], accI[4];
  gemm_core(ATr, ATi, ATin, RBr, RBi, dv, mrow0, l0, lane, accR, accI);
  int rbase = (lane >> 4) * 4;
  #pragma unroll
  for (int t = 0; t < 4; t++) {
    int l = l0 + t*16 + (lane & 15);
    float2 a1 = A1h[((size_t)(dv*64 + mBlk))*LSEQ + l];
    const float2* kp = K10h + ((size_t)(dv*LSEQ + l))*64 + wave*16 + rbase;
    #pragma unroll
    for (int r = 0; r < 4; r++) {
      float2 k10 = kp[r];
      float cx = a1.x*k10.x - a1.y*k10.y;
      float cy = a1.x*k10.y + a1.y*k10.x;
      int chain = mBlk*64 + wave*16 + rbase + r;
      big[(size_t)chain*NFP + l] = pack_c(make_float2(accR[t][r] - cx, accI[t][r] - cy));
    }
  }
}

// ---------------- Ku: u (b,l,512) -> ut[div][b][h][l] ----------------
__global__ __launch_bounds__(256) void ssm_ku(const float* __restrict__ u, float* __restrict__ ut) {
  __shared__ float s[16][513];
  int b  = blockIdx.x >> 7;
  int l0 = (blockIdx.x & 127) << 4;
  int tid = threadIdx.x;
  for (int q = tid; q < 16*512; q += 256) {
    int ll = q >> 9, dd = q & 511;
    s[ll][dd] = u[((size_t)b*LSEQ + l0 + ll)*512 + dd];
  }
  __syncthreads();
  for (int q = tid; q < 16*512; q += 256) {
    int d = q >> 4, ll = q & 15;
    int dvv = d & 7, h = d >> 3;
    ut[(((size_t)(dvv*NB + b))*HD + h)*LSEQ + l0 + ll] = s[ll][d];
  }
}

// ---------------- K3: ud[dst][f] = rfft_4096(pad(ut chain cbase+bid)), bf16x2 out ----------------
__global__ __launch_bounds__(256, 6) void ssm_k3(const float* __restrict__ ut,
                                                 unsigned* __restrict__ ud, int cbase) {
  __shared__ float2 bb[FFT_BUF];
  int tid = threadIdx.x;
  const float2* src = (const float2*)(ut + ((size_t)(cbase + blockIdx.x)) * LSEQ);
  unsigned* dst = ud + (size_t)blockIdx.x * NF;
  r8g_f32pad_fwd(src, bb);      // stage 1 (global, zero-pad fused)
  r8_ip<-1, 8>(bb);
  r8_ip<-1, 64>(bb);
  r4f_ip<-1>(bb);               // bb = Z natural order
  __syncthreads();
  for (int f = tid; f <= 2048; f += 256) {
    int fa = f & 2047, fb = (2048 - f) & 2047;
    float2 Zf = bb[SL(fa)];
    float2 Zm = bb[SL(fb)];
    float Ex = (Zf.x + Zm.x)*0.5f, Ey = (Zf.y - Zm.y)*0.5f;
    float Dx = Zf.x - Zm.x,        Dy = Zf.y + Zm.y;
    float Ox = Dy*0.5f, Oy = -Dx*0.5f;
    float s, c2;
    __sincosf(-6.28318530717958647f * (float)f * (1.0f/4096.0f), &s, &c2);
    float WOx = Ox*c2 - Oy*s, WOy = Ox*s + Oy*c2;
    dst[f] = pack_c(make_float2(Ex + WOx, Ey + WOy));
  }
}

// ---------------- K2: in-place per chain: ar row (2048 bf16x2) -> Kd row (2049) ----------------
__global__ __launch_bounds__(256, 6) void ssm_k2(unsigned* __restrict__ big) {
  __shared__ float2 bb[FFT_BUF];
  int tid = threadIdx.x;
  unsigned* row = big + (size_t)blockIdx.x * NFP;
  float2 ev[4];
  #pragma unroll
  for (int k = 0; k < 4; k++) {
    int l = tid + 256*k;
    float2 a = unpack_c(row[l]);
    float2 b = unpack_c(row[(2048 - l) & 2047]);
    ev[k] = make_float2((a.x + b.x)*0.5f, (a.y - b.y)*0.5f);
  }
  float ev1024 = (tid == 0) ? unpack_c(row[1024]).x : 0.f;
  r8g_bf16_inv(row, bb);        // inverse stage 1 (reads global)
  #pragma unroll
  for (int k = 0; k < 4; k++) { int l = tid + 256*k; row[2*l] = pack_c(ev[k]); }
  if (tid == 0) row[2048] = pack_c(make_float2(ev1024, 0.f));
  r8_ip<1, 8>(bb);
  r8_ip<1, 64>(bb);
  r4f_mod_ip(bb);               // inverse final r4 + Re*sc*mod (in-place)
  r8_ip<-1, 1>(bb);             // forward stage 1
  r8_ip<-1, 8>(bb);
  r8_ip<-1, 64>(bb);
  r4f_gw_bf16(bb, row);         // forward final r4, odd bins k<1024 to global
}

// ---------------- K4: yf[b*64+i][f] = sum_j Kd[i*64+j][f]*ud[b*64+j][f] ----------------
// grid (257 f-tiles of 8, 4 i-tiles of 16); 256 thr = 16 i x 4 j-chunks x 4 f-lanes
__global__ __launch_bounds__(256) void ssm_k4(
    const unsigned* __restrict__ kdt, const unsigned* __restrict__ ud,
    float2* __restrict__ yf) {
  __shared__ unsigned uds[NB][64][8];   // 16 KB bf16-packed
  int tid = threadIdx.x;
  int f0 = blockIdx.x * 8;
  int i0 = blockIdx.y * 16;
  int ii = tid >> 4;            // [0,16)
  int jj = (tid >> 2) & 3;      // [0,4)   (lane bits 2-3)
  int fl = tid & 3;             // [0,4)
  int i = i0 + ii;
  for (int q = tid; q < NB*64*8; q += 256) {
    int b = q >> 9, j = (q >> 3) & 63, fq = q & 7;
    int f_ = f0 + fq;
    uds[b][j][fq] = (f_ < NF) ? ud[((size_t)(b*HD + j))*NF + f_] : 0u;
  }
  __syncthreads();
  float2 acc[2][NB];
  #pragma unroll
  for (int e = 0; e < 2; e++)
    #pragma unroll
    for (int b = 0; b < NB; b++) acc[e][b] = make_float2(0.f, 0.f);
  #pragma unroll 4
  for (int jt = 0; jt < 16; jt++) {
    int j = jj*16 + jt;
    const unsigned* kp = kdt + ((size_t)(i*HD + j))*NFP + f0 + fl*2;
    uint2 kq = *reinterpret_cast<const uint2*>(kp);
    float2 kv0 = unpack_c(kq.x);
    float2 kv1 = unpack_c(kq.y);
    #pragma unroll
    for (int b = 0; b < NB; b++) {
      float2 u0 = unpack_c(uds[b][j][fl*2]);
      float2 u1 = unpack_c(uds[b][j][fl*2 + 1]);
      acc[0][b].x += kv0.x*u0.x - kv0.y*u0.y;
      acc[0][b].y += kv0.x*u0.y + kv0.y*u0.x;
      acc[1][b].x += kv1.x*u1.x - kv1.y*u1.y;
      acc[1][b].y += kv1.x*u1.y + kv1.y*u1.x;
    }
  }
  #pragma unroll
  for (int e = 0; e < 2; e++)
    #pragma unroll
    for (int b = 0; b < NB; b++) {
      acc[e][b].x += __shfl_xor(acc[e][b].x, 4);
      acc[e][b].y += __shfl_xor(acc[e][b].y, 4);
      acc[e][b].x += __shfl_xor(acc[e][b].x, 8);
      acc[e][b].y += __shfl_xor(acc[e][b].y, 8);
    }
  if (jj == 0) {
    #pragma unroll
    for (int b = 0; b < NB; b++) {
      size_t base = ((size_t)(b*HD + i))*NF + f0 + fl*2;
      #pragma unroll
      for (int e = 0; e < 2; e++)
        if (f0 + fl*2 + e < NF) yf[base + e] = acc[e][b];
    }
  }
}

// ---------------- K5: yt row = irfft_4096(yf row)[0:2048]; grid 512 ----------------
__global__ __launch_bounds__(256, 6) void ssm_k5(const float2* __restrict__ yf,
                                                 float* __restrict__ yt, int dv) {
  __shared__ float2 bb[FFT_BUF];
  int tid = threadIdx.x;
  int b = blockIdx.x >> 6, i = blockIdx.x & 63;
  const float2* src = yf + (size_t)(b*HD + i) * NF;
  float2* dst = (float2*)(yt + (((size_t)(dv*NB + b))*HD + i) * LSEQ);
  for (int k = tid; k < 2048; k += 256) {
    float2 Xk = src[k];
    float2 Xm = src[2048 - k];
    float Ex = (Xk.x + Xm.x)*0.5f, Ey = (Xk.y - Xm.y)*0.5f;
    float Dx = Xk.x - Xm.x,        Dy = Xk.y + Xm.y;
    float s, c;
    __sincosf(6.28318530717958647f * (float)k * (1.0f/4096.0f), &s, &c);
    float Ox = 0.5f*(Dx*c - Dy*s);
    float Oy = 0.5f*(Dx*s + Dy*c);
    bb[SL(k)] = make_float2(Ex - Oy, Ey + Ox);
  }
  r8_ip<1, 1>(bb);
  r8_ip<1, 8>(bb);
  r8_ip<1, 64>(bb);
  r4f_gw_f32h(bb, dst);         // final r4, t<1024 only, scaled direct write
}

// ---------------- T2: yt[div][b][i][t] -> out[b][t][i*8+div] ----------------
__global__ __launch_bounds__(256) void ssm_t2(const float* __restrict__ yt, float* __restrict__ out) {
  __shared__ float s[512][17];
  int b  = blockIdx.x >> 7;
  int t0 = (blockIdx.x & 127) << 4;
  int tid = threadIdx.x;
  for (int q = tid; q < 512*16; q += 256) {
    int d = q >> 4, tt = q & 15;
    int dvv = d & 7, i = d >> 3;
    s[d][tt] = yt[(((size_t)(dvv*NB + b))*HD + i)*LSEQ + t0 + tt];
  }
  __syncthreads();
  for (int q = tid; q < 512*16; q += 256) {
    int tt = q >> 9, d = q & 511;
    out[((size_t)b*LSEQ + t0 + tt)*512 + d] = s[d][tt];
  }
}

// ---------------- host ----------------
extern "C" void kernel_launch(void* const* d_in, const int* in_sizes, int n_in,
                              void* d_out, int out_size, void* d_ws, size_t ws_size,
                              hipStream_t stream) {
  const float* u    = (const float*)d_in[0];
  const float* Lre  = (const float*)d_in[1];
  const float* Lim  = (const float*)d_in[2];
  const float* Pre  = (const float*)d_in[3];
  const float* Pim  = (const float*)d_in[4];
  const float* Bre  = (const float*)d_in[5];
  const float* Bim  = (const float*)d_in[6];
  const float* Cre  = (const float*)d_in[7];
  const float* Cim  = (const float*)d_in[8];
  const float* step = (const float*)d_in[9];
  float* out = (float*)d_out;

  char* w = (char*)d_ws;
  size_t off = 0;
  auto carve = [&](size_t bytes) -> void* {
    void* p = (void*)(w + off);
    off += (bytes + 255) & ~(size_t)255;
    return p;
  };
  float2*   cpx  = (float2*)carve((size_t)NDIV*LSEQ*sizeof(float2));          // 0.13 MB
  float*    ut   = (float*) carve((size_t)NDIV*NB*HD*LSEQ*sizeof(float));     // 33.55 MB (later = yt)
  unsigned* big  = (unsigned*)carve((size_t)4096*NFP*sizeof(unsigned) + 256); // 33.62 MB (bf16x2, padded rows + tail)
  float2*   yf   = (float2*)carve((size_t)512*NF*sizeof(float2));             // 8.39 MB (per div)
  float2*   CT   = (float2*)carve((size_t)NDIV*NM*HD*sizeof(float2));         // 256 KB
  float2*   BT   = (float2*)carve((size_t)NDIV*NM*HD*sizeof(float2));         // 256 KB
  float2*   PT   = (float2*)carve((size_t)NDIV*NM*sizeof(float2));            // 4 KB
  unsigned short* ATr  = (unsigned short*)carve((size_t)NDIV*ATROWS*64*2);    // 4.33 MB
  unsigned short* ATi  = (unsigned short*)carve((size_t)NDIV*ATROWS*64*2);    // 4.33 MB
  unsigned short* ATin = (unsigned short*)carve((size_t)NDIV*ATROWS*64*2);    // 4.33 MB
  unsigned short* RBr  = (unsigned short*)carve((size_t)NDIV*8*LSEQ*8*2);     // 2.10 MB
  unsigned short* RBi  = (unsigned short*)carve((size_t)NDIV*8*LSEQ*8*2);     // 2.10 MB
  float2*   A1h  = (float2*)carve((size_t)NDIV*64*LSEQ*sizeof(float2));       // 8.39 MB
  float2*   K10h = (float2*)carve((size_t)NDIV*LSEQ*64*sizeof(float2));       // 8.39 MB
  size_t off_m = off;
  // prefer all-div ud (33.6 MB bf16); fall back to per-div (4.2 MB) if ws too small
  unsigned* ud_full = (unsigned*)carve((size_t)NDIV*512*NF*sizeof(unsigned));
  bool full = (ws_size >= off);
  unsigned* ud = ud_full;
  if (!full) {
    off = off_m;
    ud = (unsigned*)carve((size_t)512*NF*sizeof(unsigned));
    if (ws_size < off) return;   // insufficient scratch -> clean failure
  }
  (void)in_sizes; (void)n_in; (void)out_size;

  ssm_kt<<<128, 256, 0, stream>>>(Cre, Cim, Bre, Bim, Pre, Pim, CT, BT, PT);
  ssm_k0a<<<256, 256, 0, stream>>>(Lre, Lim, Pre, Pim, step, RBr, RBi, cpx);
  ssm_km<<<dim3(65, 8), 256, 0, stream>>>(CT, BT, PT, ATr, ATi, ATin);
  ssm_ku<<<1024, 256, 0, stream>>>(u, ut);
  ssm_g1<<<dim3(2, 32, 8), 256, 0, stream>>>(ATr, ATi, ATin, RBr, RBi, cpx, A1h, K10h);
  if (full) ssm_k3<<<4096, 256, 0, stream>>>(ut, ud_full, 0);
  for (int dv = 0; dv < NDIV; ++dv) {
    if (!full) ssm_k3<<<512, 256, 0, stream>>>(ut, ud, dv*512);
    const unsigned* udp = full ? (ud_full + (size_t)dv*512*NF) : ud;
    ssm_g2<<<dim3(64, 32), 256, 0, stream>>>(ATr, ATi, ATin, RBr, RBi, A1h, K10h, big, dv);
    ssm_k2<<<4096, 256, 0, stream>>>(big);
    ssm_k4<<<dim3(257, 4), 256, 0, stream>>>(big, udp, yf);
    ssm_k5<<<512, 256, 0, stream>>>(yf, ut, dv);
  }
  ssm_t2<<<1024, 256, 0, stream>>>(ut, out);
}

// Round 20
// 866.804 us; speedup vs baseline: 1.1808x; 1.1808x over previous
//
#include <hip/hip_runtime.h>
#include <hip/hip_bf16.h>
#include <math.h>

#define LSEQ 2048
#define NM   64     // N modes
#define HD   64     // H
#define NDIV 8
#define NB   8      // batch
#define NF   2049   // rfft bins of 4096
#define NFP  2052   // padded row stride for big/kdt (16B-aligned rows)
#define ATROWS 4224 // 4096 ij + 64 Mp + 64 Mq

// XOR-swizzled LDS slot: bijective involution on [0,2048); all radix-8/4
// access families land 4 lanes per bank-pair (b64 conflict-free minimum).
#define SL(E) ((E) ^ (((E) >> 4) & 15))
#define FFT_BUF 2048

typedef __attribute__((ext_vector_type(8))) short bf16x8;
typedef __attribute__((ext_vector_type(4))) float f32x4;

// ---------------- bf16 helpers ----------------
__device__ __forceinline__ unsigned pack_c(float2 v) {
  __hip_bfloat162 h = __float22bfloat162_rn(v);
  return *reinterpret_cast<unsigned*>(&h);
}
__device__ __forceinline__ float2 unpack_c(unsigned u) {
  __hip_bfloat162 h = *reinterpret_cast<__hip_bfloat162*>(&u);
  return __bfloat1622float2(h);
}
__device__ __forceinline__ unsigned short f2bf(float v) {
  __hip_bfloat16 h = __float2bfloat16(v);
  return *reinterpret_cast<unsigned short*>(&h);
}

// ---------------- complex helpers ----------------
__device__ __forceinline__ float2 cadd(float2 a, float2 b) { return make_float2(a.x+b.x, a.y+b.y); }
__device__ __forceinline__ float2 csub(float2 a, float2 b) { return make_float2(a.x-b.x, a.y-b.y); }
__device__ __forceinline__ float2 cmulf(float2 a, float2 b) {
  return make_float2(a.x*b.x - a.y*b.y, a.x*b.y + a.y*b.x);
}

struct cplxd { double x, y; };
__device__ __forceinline__ cplxd cmuld(cplxd a, cplxd b) {
  return {a.x*b.x - a.y*b.y, a.x*b.y + a.y*b.x};
}
__device__ __forceinline__ cplxd cdivd(cplxd a, cplxd b) {
  double inv = 1.0 / (b.x*b.x + b.y*b.y);
  return {(a.x*b.x + a.y*b.y)*inv, (a.y*b.x - a.x*b.y)*inv};
}

// ---------------- 8-point DFT in registers (a[0..7] in/out) ----------------
template<int SIGN>
__device__ __forceinline__ void dft8(float2* a) {
  const float R = 0.70710678118654752f;
  float2 e0 = cadd(a[0], a[4]), e1 = cadd(a[2], a[6]);
  float2 d0 = csub(a[0], a[4]), d1 = csub(a[2], a[6]);
  float2 t0 = cadd(e0, e1), t2 = csub(e0, e1);
  float2 t1, t3;
  if (SIGN < 0) { t1 = make_float2(d0.x + d1.y, d0.y - d1.x);
                  t3 = make_float2(d0.x - d1.y, d0.y + d1.x); }
  else          { t1 = make_float2(d0.x - d1.y, d0.y + d1.x);
                  t3 = make_float2(d0.x + d1.y, d0.y - d1.x); }
  float2 f0 = cadd(a[1], a[5]), f1 = cadd(a[3], a[7]);
  float2 g0 = csub(a[1], a[5]), g1 = csub(a[3], a[7]);
  float2 s0 = cadd(f0, f1), s2 = csub(f0, f1);
  float2 s1, s3;
  if (SIGN < 0) { s1 = make_float2(g0.x + g1.y, g0.y - g1.x);
                  s3 = make_float2(g0.x - g1.y, g0.y + g1.x); }
  else          { s1 = make_float2(g0.x - g1.y, g0.y + g1.x);
                  s3 = make_float2(g0.x + g1.y, g0.y - g1.x); }
  float2 r1, r2, r3;
  if (SIGN < 0) {
    r1 = make_float2(R*(s1.x + s1.y), R*(s1.y - s1.x));
    r2 = make_float2(s2.y, -s2.x);
    r3 = make_float2(R*(s3.y - s3.x), -R*(s3.x + s3.y));
  } else {
    r1 = make_float2(R*(s1.x - s1.y), R*(s1.x + s1.y));
    r2 = make_float2(-s2.y, s2.x);
    r3 = make_float2(-R*(s3.x + s3.y), R*(s3.x - s3.y));
  }
  a[0] = cadd(t0, s0); a[4] = csub(t0, s0);
  a[1] = cadd(t1, r1); a[5] = csub(t1, r1);
  a[2] = cadd(t2, r2); a[6] = csub(t2, r2);
  a[3] = cadd(t3, r3); a[7] = csub(t3, r3);
}

// ---------------- Stockham radix-8 stage, LDS->LDS; 1 butterfly/thread ----------------
template<int SIGN, int M>
__device__ __forceinline__ void r8_stage(const float2* __restrict__ src,
                                         float2* __restrict__ dst) {
  __syncthreads();
  int idx = (int)threadIdx.x;          // [0,256)
  int q = idx / M, p = idx - q*M;
  float2 a[8];
  #pragma unroll
  for (int v = 0; v < 8; v++) a[v] = src[SL(idx + 256*v)];
  if constexpr (M > 1) {
    float s, c;
    __sincosf(-6.28318530717958647f * (float)p / (8.0f * (float)M), &s, &c);
    if (SIGN > 0) s = -s;
    float2 W1 = make_float2(c, s);
    float2 W2 = cmulf(W1, W1);
    float2 W3 = cmulf(W2, W1);
    float2 W4 = cmulf(W2, W2);
    float2 W5 = cmulf(W3, W2);
    float2 W6 = cmulf(W3, W3);
    float2 W7 = cmulf(W4, W3);
    a[1] = cmulf(a[1], W1); a[2] = cmulf(a[2], W2); a[3] = cmulf(a[3], W3);
    a[4] = cmulf(a[4], W4); a[5] = cmulf(a[5], W5); a[6] = cmulf(a[6], W6);
    a[7] = cmulf(a[7], W7);
  }
  dft8<SIGN>(a);
  int ob = q * 8 * M + p;
  #pragma unroll
  for (int u = 0; u < 8; u++) dst[SL(ob + u*M)] = a[u];
}

// k2 FFT#1 stage 1 (SIGN=+1, M=1): reads bf16 row direct from global (no twiddle)
__device__ __forceinline__ void r8g_bf16_inv(const unsigned* __restrict__ row,
                                             float2* __restrict__ dst) {
  int idx = (int)threadIdx.x;
  float2 a[8];
  #pragma unroll
  for (int v = 0; v < 8; v++) a[v] = unpack_c(row[idx + 256*v]);
  dft8<1>(a);
  int ob = idx * 8;
  #pragma unroll
  for (int u = 0; u < 8; u++) dst[SL(ob + u)] = a[u];
}

// k3 stage 1 (SIGN=-1, M=1): reads f32 z-pairs from global, upper half zero
__device__ __forceinline__ void r8g_f32pad_fwd(const float2* __restrict__ g,
                                               float2* __restrict__ dst) {
  int idx = (int)threadIdx.x;
  float2 a[8];
  #pragma unroll
  for (int v = 0; v < 4; v++) a[v] = g[idx + 256*v];
  #pragma unroll
  for (int v = 4; v < 8; v++) a[v] = make_float2(0.f, 0.f);
  dft8<-1>(a);
  int ob = idx * 8;
  #pragma unroll
  for (int u = 0; u < 8; u++) dst[SL(ob + u)] = a[u];
}

// final radix-4 (M=512) LDS->LDS, full output
template<int SIGN>
__device__ __forceinline__ void r4f_ldst(const float2* __restrict__ src,
                                         float2* __restrict__ dst) {
  __syncthreads();
  #pragma unroll
  for (int t = 0; t < 2; t++) {
    int p = (int)threadIdx.x + t * 256;
    float2 a0 = src[SL(p)], a1 = src[SL(p + 512)];
    float2 a2 = src[SL(p + 1024)], a3 = src[SL(p + 1536)];
    float s, c;
    __sincosf(-6.28318530717958647f * (float)p * (1.0f/2048.0f), &s, &c);
    if (SIGN > 0) s = -s;
    float2 W1 = make_float2(c, s);
    float2 W2 = cmulf(W1, W1);
    float2 W3 = cmulf(W2, W1);
    float2 b1 = cmulf(a1, W1), b2 = cmulf(a2, W2), b3 = cmulf(a3, W3);
    float2 e0 = cadd(a0, b2), e1 = cadd(b1, b3);
    float2 d0 = csub(a0, b2), d1 = csub(b1, b3);
    float2 o1, o3;
    if (SIGN < 0) { o1 = make_float2(d0.x + d1.y, d0.y - d1.x);
                    o3 = make_float2(d0.x - d1.y, d0.y + d1.x); }
    else          { o1 = make_float2(d0.x - d1.y, d0.y + d1.x);
                    o3 = make_float2(d0.x + d1.y, d0.y - d1.x); }
    dst[SL(p)]        = cadd(e0, e1);
    dst[SL(p + 512)]  = o1;
    dst[SL(p + 1024)] = csub(e0, e1);
    dst[SL(p + 1536)] = o3;
  }
}

// k2: final r4 of the INVERSE fft fused with Re()*(1/2048)*mod, mod=e^{-i*pi*t/2048}
__device__ __forceinline__ void r4f_mod(const float2* __restrict__ src,
                                        float2* __restrict__ dst) {
  __syncthreads();
  const float sc = 1.0f/2048.0f;
  const float R = 0.70710678118654752f;
  #pragma unroll
  for (int t = 0; t < 2; t++) {
    int p = (int)threadIdx.x + t * 256;
    float2 a0 = src[SL(p)], a1 = src[SL(p + 512)];
    float2 a2 = src[SL(p + 1024)], a3 = src[SL(p + 1536)];
    float s, c;
    __sincosf(-6.28318530717958647f * (float)p * (1.0f/2048.0f), &s, &c);
    float2 W1 = make_float2(c, -s);          // inverse twiddle
    float2 W2 = cmulf(W1, W1);
    float2 W3 = cmulf(W2, W1);
    float2 b1 = cmulf(a1, W1), b2 = cmulf(a2, W2), b3 = cmulf(a3, W3);
    float2 e0 = cadd(a0, b2), e1 = cadd(b1, b3);
    float2 d0 = csub(a0, b2), d1 = csub(b1, b3);
    float kr0 = (e0.x + e1.x) * sc;          // z[p]
    float kr1 = (d0.x - d1.y) * sc;          // z[p+512]  (inverse o1.x)
    float kr2 = (e0.x - e1.x) * sc;          // z[p+1024]
    float kr3 = (d0.x + d1.y) * sc;          // z[p+1536] (inverse o3.x)
    float ms, mc;
    __sincosf(-3.14159265358979324f * (float)p * (1.0f/2048.0f), &ms, &mc);
    dst[SL(p)]        = make_float2(kr0*mc,           kr0*ms);
    dst[SL(p + 512)]  = make_float2(kr1*R*(mc + ms),  kr1*R*(ms - mc));
    dst[SL(p + 1024)] = make_float2(kr2*ms,          -kr2*mc);
    dst[SL(p + 1536)] = make_float2(kr3*R*(ms - mc), -kr3*R*(mc + ms));
  }
}

// k2 forward final r4 (SIGN=-1): write odd bins 2k+1 (k<1024 only!) packed bf16.
// k = p (u=0) and p+512 (u=1); u=2,3 map to bins > 2048 (conjugate half) - dropped.
__device__ __forceinline__ void r4f_gw_bf16(const float2* __restrict__ src,
                                            unsigned* __restrict__ row) {
  __syncthreads();
  #pragma unroll
  for (int t = 0; t < 2; t++) {
    int p = (int)threadIdx.x + t * 256;
    float2 a0 = src[SL(p)], a1 = src[SL(p + 512)];
    float2 a2 = src[SL(p + 1024)], a3 = src[SL(p + 1536)];
    float s, c;
    __sincosf(-6.28318530717958647f * (float)p * (1.0f/2048.0f), &s, &c);
    float2 W1 = make_float2(c, s);
    float2 W2 = cmulf(W1, W1);
    float2 W3 = cmulf(W2, W1);
    float2 b1 = cmulf(a1, W1), b2 = cmulf(a2, W2), b3 = cmulf(a3, W3);
    float2 e0 = cadd(a0, b2), e1 = cadd(b1, b3);
    float2 d0 = csub(a0, b2), d1 = csub(b1, b3);
    float2 z0 = cadd(e0, e1);                               // k = p
    float2 z1 = make_float2(d0.x + d1.y, d0.y - d1.x);      // k = p+512
    row[2*p + 1]       = pack_c(z0);
    row[2*(p+512) + 1] = pack_c(z1);
  }
}

// k5 final r4 (SIGN=+1): only t<1024 needed; scaled; writes f32 pairs to global
__device__ __forceinline__ void r4f_gw_f32h(const float2* __restrict__ src,
                                            float2* __restrict__ dst) {
  __syncthreads();
  const float sc = 1.0f/2048.0f;
  #pragma unroll
  for (int t = 0; t < 2; t++) {
    int p = (int)threadIdx.x + t * 256;
    float2 a0 = src[SL(p)], a1 = src[SL(p + 512)];
    float2 a2 = src[SL(p + 1024)], a3 = src[SL(p + 1536)];
    float s, c;
    __sincosf(-6.28318530717958647f * (float)p * (1.0f/2048.0f), &s, &c);
    float2 W1 = make_float2(c, -s);          // inverse twiddle
    float2 W2 = cmulf(W1, W1);
    float2 W3 = cmulf(W2, W1);
    float2 b1 = cmulf(a1, W1), b2 = cmulf(a2, W2), b3 = cmulf(a3, W3);
    float2 e0 = cadd(a0, b2), e1 = cadd(b1, b3);
    float2 d0 = csub(a0, b2), d1 = csub(b1, b3);
    float2 z0 = cadd(e0, e1);
    float2 z1 = make_float2(d0.x - d1.y, d0.y + d1.x);
    dst[p]       = make_float2(z0.x*sc, z0.y*sc);
    dst[p + 512] = make_float2(z1.x*sc, z1.y*sc);
  }
}

// ---------------- KT: params -> div-major coalesced layouts ----------------
__global__ __launch_bounds__(256) void ssm_kt(
    const float* __restrict__ Cre, const float* __restrict__ Cim,
    const float* __restrict__ Bre, const float* __restrict__ Bim,
    const float* __restrict__ Pre, const float* __restrict__ Pim,
    float2* __restrict__ CT, float2* __restrict__ BT, float2* __restrict__ PT) {
  int idx = blockIdx.x * 256 + threadIdx.x;   // 32768 = dv*4096 + n*64 + x
  int dv = idx >> 12, n = (idx >> 6) & 63, x = idx & 63;
  CT[idx] = make_float2(Cre[((size_t)x*NM + n)*NDIV + dv], -Cim[((size_t)x*NM + n)*NDIV + dv]);
  BT[idx] = make_float2(Bre[((size_t)n*HD + x)*NDIV + dv],  Bim[((size_t)n*HD + x)*NDIV + dv]);
  if (idx < NDIV*NM) {
    int dv2 = idx >> 6, n2 = idx & 63;
    PT[idx] = make_float2(Pre[n2*NDIV + dv2], Pim[n2*NDIV + dv2]);
  }
}

// ---------------- K0a: rcb bf16 planes (k-interleaved) + cpx ----------------
__global__ __launch_bounds__(256) void ssm_k0a(
    const float* __restrict__ Lre, const float* __restrict__ Lim,
    const float* __restrict__ Pre, const float* __restrict__ Pim,
    const float* __restrict__ step, unsigned short* __restrict__ RBr,
    unsigned short* __restrict__ RBi, float2* __restrict__ cpx) {
  int idx = blockIdx.x * 256 + threadIdx.x;     // 65536 = (dv*2048 + l)*4 + qn
  int qn = idx & 3;
  int rest = idx >> 2;
  int l = rest & (LSEQ - 1);
  int dv = rest >> 11;
  double s = (double)expf(step[0]);
  float angf = -6.2831855f * ((float)l * (1.0f/2048.0f));
  double si, co;
  sincos((double)angf, &si, &co);
  cplxd om    = {co, si};
  cplxd one_p = {1.0 + om.x,  om.y};
  double ts = 2.0 / s;
  cplxd g = cdivd({ts*(1.0 - om.x), ts*(-om.y)}, one_p);
  cplxd c = cdivd({2.0, 0.0}, one_p);
  double k11x = 0.0, k11y = 0.0;
  for (int u = 0; u < 16; u++) {
    int n = qn*16 + u;
    float lre = fminf(Lre[n*NDIV+dv], -0.0001f);
    float lim = Lim[n*NDIV+dv];
    cplxd den = {g.x - (double)lre, g.y - (double)lim};
    cplxd r   = cdivd({1.0, 0.0}, den);
    cplxd rcv = cmuld(c, r);
    size_t bidx = (((size_t)(dv*8 + (n >> 3)))*LSEQ + l)*8 + (n & 7);
    RBr[bidx] = f2bf((float)rcv.x);
    RBi[bidx] = f2bf((float)rcv.y);
    double pr = (double)Pre[n*NDIV+dv], pi = (double)Pim[n*NDIV+dv];
    double p2 = pr*pr + pi*pi;                  // conj(p)*p is real
    k11x += p2 * rcv.x; k11y += p2 * rcv.y;
  }
  k11x += __shfl_xor(k11x, 1); k11y += __shfl_xor(k11y, 1);
  k11x += __shfl_xor(k11x, 2); k11y += __shfl_xor(k11y, 2);
  if (qn == 0)
    cpx[(size_t)dv*LSEQ + l] = make_float2((float)(c.x + k11x), (float)(c.y + k11y));
}

// ---------------- KM: build AT planes (rows: 4096 ij, 64 Mp, 64 Mq) ----------------
__global__ __launch_bounds__(256) void ssm_km(
    const float2* __restrict__ CT, const float2* __restrict__ BT,
    const float2* __restrict__ PT, unsigned short* __restrict__ ATr,
    unsigned short* __restrict__ ATi, unsigned short* __restrict__ ATin) {
  __shared__ float2 PAN[4096];   // 32 KB
  __shared__ float2 ROW[64];
  int dv = blockIdx.y;
  int ib = blockIdx.x;           // 0..63 = i; 64 = Mp/Mq block
  int tid = threadIdx.x;
  if (ib < 64) {
    for (int q = tid; q < 4096; q += 256) PAN[q] = BT[(size_t)dv*4096 + q];  // [n][j]
    if (tid < 64) ROW[tid] = CT[(size_t)dv*4096 + tid*64 + ib];              // CC[ib][n]
    __syncthreads();
    int j = tid >> 2, nq = tid & 3;
    size_t rbase = ((size_t)dv*ATROWS + ib*64 + j)*64;
    for (int u = 0; u < 16; u++) {
      int n = nq*16 + u;
      float2 cv = ROW[n];
      float2 bv = PAN[n*64 + j];
      float xr = cv.x*bv.x - cv.y*bv.y, xi = cv.x*bv.y + cv.y*bv.x;
      ATr[rbase + n] = f2bf(xr); ATi[rbase + n] = f2bf(xi); ATin[rbase + n] = f2bf(-xi);
    }
  } else {
    for (int q = tid; q < 4096; q += 256) PAN[q] = CT[(size_t)dv*4096 + q];  // [n][x]
    if (tid < 64) ROW[tid] = PT[dv*64 + tid];
    __syncthreads();
    int x = tid >> 2, nq = tid & 3;
    size_t pbase = ((size_t)dv*ATROWS + 4096 + x)*64;
    for (int u = 0; u < 16; u++) {
      int n = nq*16 + u;
      float2 cv = PAN[n*64 + x];
      float2 pv = ROW[n];
      float xr = cv.x*pv.x - cv.y*pv.y, xi = cv.x*pv.y + cv.y*pv.x;
      ATr[pbase + n] = f2bf(xr); ATi[pbase + n] = f2bf(xi); ATin[pbase + n] = f2bf(-xi);
    }
    __syncthreads();
    for (int q = tid; q < 4096; q += 256) PAN[q] = BT[(size_t)dv*4096 + q];
    __syncthreads();
    size_t qbase = ((size_t)dv*ATROWS + 4160 + x)*64;
    for (int u = 0; u < 16; u++) {
      int n = nq*16 + u;
      float2 bv = PAN[n*64 + x];
      float2 pv = ROW[n];
      float xr = pv.x*bv.x + pv.y*bv.y, xi = pv.x*bv.y - pv.y*bv.x;
      ATr[qbase + n] = f2bf(xr); ATi[qbase + n] = f2bf(xi); ATin[qbase + n] = f2bf(-xi);
    }
  }
}

// ---------------- MFMA GEMM core ----------------
__device__ __forceinline__ void gemm_core(
    const unsigned short* __restrict__ ATr, const unsigned short* __restrict__ ATi,
    const unsigned short* __restrict__ ATin, const unsigned short* __restrict__ RBr,
    const unsigned short* __restrict__ RBi, int dv, int mrow0, int l0, int lane,
    f32x4 accR[4], f32x4 accI[4]) {
  int mloc = lane & 15, kgrp = lane >> 4;
  #pragma unroll
  for (int t = 0; t < 4; t++) {
    accR[t] = (f32x4){0.f, 0.f, 0.f, 0.f};
    accI[t] = (f32x4){0.f, 0.f, 0.f, 0.f};
  }
  size_t abase = ((size_t)dv*ATROWS + mrow0 + mloc)*64 + kgrp*8;
  #pragma unroll
  for (int s = 0; s < 2; s++) {
    bf16x8 ar = *reinterpret_cast<const bf16x8*>(ATr  + abase + s*32);
    bf16x8 ai = *reinterpret_cast<const bf16x8*>(ATi  + abase + s*32);
    bf16x8 an = *reinterpret_cast<const bf16x8*>(ATin + abase + s*32);
    size_t bbase = (((size_t)(dv*8 + s*4 + kgrp))*LSEQ + l0 + mloc)*8;
    #pragma unroll
    for (int t = 0; t < 4; t++) {
      bf16x8 br = *reinterpret_cast<const bf16x8*>(RBr + bbase + t*128);
      bf16x8 bi = *reinterpret_cast<const bf16x8*>(RBi + bbase + t*128);
      accR[t] = __builtin_amdgcn_mfma_f32_16x16x32_bf16(ar, br, accR[t], 0, 0, 0);
      accR[t] = __builtin_amdgcn_mfma_f32_16x16x32_bf16(an, bi, accR[t], 0, 0, 0);
      accI[t] = __builtin_amdgcn_mfma_f32_16x16x32_bf16(ar, bi, accI[t], 0, 0, 0);
      accI[t] = __builtin_amdgcn_mfma_f32_16x16x32_bf16(ai, br, accI[t], 0, 0, 0);
    }
  }
}

// ---------------- G1: Woodbury vectors ----------------
__global__ __launch_bounds__(256) void ssm_g1(
    const unsigned short* __restrict__ ATr, const unsigned short* __restrict__ ATi,
    const unsigned short* __restrict__ ATin, const unsigned short* __restrict__ RBr,
    const unsigned short* __restrict__ RBi, const float2* __restrict__ cpx,
    float2* __restrict__ A1h, float2* __restrict__ K10h) {
  int which = blockIdx.x;          // 0 = Mp -> A1h, 1 = Mq -> K10h
  int nBlk = blockIdx.y;
  int dv = blockIdx.z;
  int wave = threadIdx.x >> 6, lane = threadIdx.x & 63;
  int mrow0 = 4096 + which*64 + wave*16;
  int l0 = nBlk * 64;
  f32x4 accR[4], accI[4];
  gemm_core(ATr, ATi, ATin, RBr, RBi, dv, mrow0, l0, lane, accR, accI);
  int rbase = (lane >> 4) * 4;
  #pragma unroll
  for (int t = 0; t < 4; t++) {
    int l = l0 + t*16 + (lane & 15);
    if (which == 0) {
      float2 w = cpx[((size_t)dv << 11) + l];
      float inv = 1.0f / (w.x*w.x + w.y*w.y);
      #pragma unroll
      for (int r = 0; r < 4; r++) {
        int x = wave*16 + rbase + r;
        float sx = accR[t][r], sy = accI[t][r];
        A1h[((size_t)(dv*64 + x))*LSEQ + l] =
            make_float2((sx*w.x + sy*w.y)*inv, (sy*w.x - sx*w.y)*inv);
      }
    } else {
      #pragma unroll
      for (int r = 0; r < 4; r++) {
        int x = wave*16 + rbase + r;
        K10h[((size_t)(dv*LSEQ + l))*64 + x] = make_float2(accR[t][r], accI[t][r]);
      }
    }
  }
}

// ---------------- G2: at_roots GEMM + rank-1 correction ----------------
__global__ __launch_bounds__(256) void ssm_g2(
    const unsigned short* __restrict__ ATr, const unsigned short* __restrict__ ATi,
    const unsigned short* __restrict__ ATin, const unsigned short* __restrict__ RBr,
    const unsigned short* __restrict__ RBi, const float2* __restrict__ A1h,
    const float2* __restrict__ K10h, unsigned* __restrict__ big, int dv) {
  int mBlk = blockIdx.x;           // = i
  int nBlk = blockIdx.y;
  int wave = threadIdx.x >> 6, lane = threadIdx.x & 63;
  int mrow0 = mBlk*64 + wave*16;
  int l0 = nBlk * 64;
  f32x4 accR[4], accI[4];
  gemm_core(ATr, ATi, ATin, RBr, RBi, dv, mrow0, l0, lane, accR, accI);
  int rbase = (lane >> 4) * 4;
  #pragma unroll
  for (int t = 0; t < 4; t++) {
    int l = l0 + t*16 + (lane & 15);
    float2 a1 = A1h[((size_t)(dv*64 + mBlk))*LSEQ + l];
    const float2* kp = K10h + ((size_t)(dv*LSEQ + l))*64 + wave*16 + rbase;
    #pragma unroll
    for (int r = 0; r < 4; r++) {
      float2 k10 = kp[r];
      float cx = a1.x*k10.x - a1.y*k10.y;
      float cy = a1.x*k10.y + a1.y*k10.x;
      int chain = mBlk*64 + wave*16 + rbase + r;
      big[(size_t)chain*NFP + l] = pack_c(make_float2(accR[t][r] - cx, accI[t][r] - cy));
    }
  }
}

// ---------------- Ku: u (b,l,512) -> ut[div][b][h][l] ----------------
__global__ __launch_bounds__(256) void ssm_ku(const float* __restrict__ u, float* __restrict__ ut) {
  __shared__ float s[16][513];
  int b  = blockIdx.x >> 7;
  int l0 = (blockIdx.x & 127) << 4;
  int tid = threadIdx.x;
  for (int q = tid; q < 16*512; q += 256) {
    int ll = q >> 9, dd = q & 511;
    s[ll][dd] = u[((size_t)b*LSEQ + l0 + ll)*512 + dd];
  }
  __syncthreads();
  for (int q = tid; q < 16*512; q += 256) {
    int d = q >> 4, ll = q & 15;
    int dvv = d & 7, h = d >> 3;
    ut[(((size_t)(dvv*NB + b))*HD + h)*LSEQ + l0 + ll] = s[ll][d];
  }
}

// ---------------- K3: ud[dst][f] = rfft_4096(pad(ut chain cbase+bid)), bf16x2 out ----------------
__global__ __launch_bounds__(256) void ssm_k3(const float* __restrict__ ut,
                                              unsigned* __restrict__ ud, int cbase) {
  __shared__ float2 b0[FFT_BUF];
  __shared__ float2 b1[FFT_BUF];
  int tid = threadIdx.x;
  const float2* src = (const float2*)(ut + ((size_t)(cbase + blockIdx.x)) * LSEQ);
  unsigned* dst = ud + (size_t)blockIdx.x * NF;
  r8g_f32pad_fwd(src, b1);      // stage 1 (global, zero-pad fused)
  r8_stage<-1, 8>(b1, b0);
  r8_stage<-1, 64>(b0, b1);
  r4f_ldst<-1>(b1, b0);         // b0 = Z natural order
  __syncthreads();
  for (int f = tid; f <= 2048; f += 256) {
    int fa = f & 2047, fb = (2048 - f) & 2047;
    float2 Zf = b0[SL(fa)];
    float2 Zm = b0[SL(fb)];
    float Ex = (Zf.x + Zm.x)*0.5f, Ey = (Zf.y - Zm.y)*0.5f;
    float Dx = Zf.x - Zm.x,        Dy = Zf.y + Zm.y;
    float Ox = Dy*0.5f, Oy = -Dx*0.5f;
    float s, c2;
    __sincosf(-6.28318530717958647f * (float)f * (1.0f/4096.0f), &s, &c2);
    float WOx = Ox*c2 - Oy*s, WOy = Ox*s + Oy*c2;
    dst[f] = pack_c(make_float2(Ex + WOx, Ey + WOy));
  }
}

// ---------------- K2: in-place per chain: ar row (2048 bf16x2) -> Kd row (2049) ----------------
__global__ __launch_bounds__(256) void ssm_k2(unsigned* __restrict__ big) {
  __shared__ float2 b0[FFT_BUF];
  __shared__ float2 b1[FFT_BUF];
  int tid = threadIdx.x;
  unsigned* row = big + (size_t)blockIdx.x * NFP;
  float2 ev[4];
  #pragma unroll
  for (int k = 0; k < 4; k++) {
    int l = tid + 256*k;
    float2 a = unpack_c(row[l]);
    float2 b = unpack_c(row[(2048 - l) & 2047]);
    ev[k] = make_float2((a.x + b.x)*0.5f, (a.y - b.y)*0.5f);
  }
  float ev1024 = (tid == 0) ? unpack_c(row[1024]).x : 0.f;
  r8g_bf16_inv(row, b1);        // inverse stage 1 (reads global)
  __syncthreads();              // all global reads of row complete
  #pragma unroll
  for (int k = 0; k < 4; k++) { int l = tid + 256*k; row[2*l] = pack_c(ev[k]); }
  if (tid == 0) row[2048] = pack_c(make_float2(ev1024, 0.f));
  r8_stage<1, 8>(b1, b0);
  r8_stage<1, 64>(b0, b1);
  r4f_mod(b1, b0);              // inverse final r4 + Re*sc*mod -> b0
  r8_stage<-1, 1>(b0, b1);      // forward stage 1
  r8_stage<-1, 8>(b1, b0);
  r8_stage<-1, 64>(b0, b1);
  r4f_gw_bf16(b1, row);         // forward final r4, odd bins k<1024 to global
}

// ---------------- K4: yf[b*64+i][f] = sum_j Kd[i*64+j][f]*ud[b*64+j][f] ----------------
// grid (257 f-tiles of 8, 4 i-tiles of 16); 256 thr = 16 i x 4 j-chunks x 4 f-lanes
__global__ __launch_bounds__(256) void ssm_k4(
    const unsigned* __restrict__ kdt, const unsigned* __restrict__ ud,
    float2* __restrict__ yf) {
  __shared__ unsigned uds[NB][64][8];   // 16 KB bf16-packed
  int tid = threadIdx.x;
  int f0 = blockIdx.x * 8;
  int i0 = blockIdx.y * 16;
  int ii = tid >> 4;            // [0,16)
  int jj = (tid >> 2) & 3;      // [0,4)   (lane bits 2-3)
  int fl = tid & 3;             // [0,4)
  int i = i0 + ii;
  for (int q = tid; q < NB*64*8; q += 256) {
    int b = q >> 9, j = (q >> 3) & 63, fq = q & 7;
    int f_ = f0 + fq;
    uds[b][j][fq] = (f_ < NF) ? ud[((size_t)(b*HD + j))*NF + f_] : 0u;
  }
  __syncthreads();
  float2 acc[2][NB];
  #pragma unroll
  for (int e = 0; e < 2; e++)
    #pragma unroll
    for (int b = 0; b < NB; b++) acc[e][b] = make_float2(0.f, 0.f);
  #pragma unroll 4
  for (int jt = 0; jt < 16; jt++) {
    int j = jj*16 + jt;
    const unsigned* kp = kdt + ((size_t)(i*HD + j))*NFP + f0 + fl*2;
    uint2 kq = *reinterpret_cast<const uint2*>(kp);
    float2 kv0 = unpack_c(kq.x);
    float2 kv1 = unpack_c(kq.y);
    #pragma unroll
    for (int b = 0; b < NB; b++) {
      float2 u0 = unpack_c(uds[b][j][fl*2]);
      float2 u1 = unpack_c(uds[b][j][fl*2 + 1]);
      acc[0][b].x += kv0.x*u0.x - kv0.y*u0.y;
      acc[0][b].y += kv0.x*u0.y + kv0.y*u0.x;
      acc[1][b].x += kv1.x*u1.x - kv1.y*u1.y;
      acc[1][b].y += kv1.x*u1.y + kv1.y*u1.x;
    }
  }
  #pragma unroll
  for (int e = 0; e < 2; e++)
    #pragma unroll
    for (int b = 0; b < NB; b++) {
      acc[e][b].x += __shfl_xor(acc[e][b].x, 4);
      acc[e][b].y += __shfl_xor(acc[e][b].y, 4);
      acc[e][b].x += __shfl_xor(acc[e][b].x, 8);
      acc[e][b].y += __shfl_xor(acc[e][b].y, 8);
    }
  if (jj == 0) {
    #pragma unroll
    for (int b = 0; b < NB; b++) {
      size_t base = ((size_t)(b*HD + i))*NF + f0 + fl*2;
      #pragma unroll
      for (int e = 0; e < 2; e++)
        if (f0 + fl*2 + e < NF) yf[base + e] = acc[e][b];
    }
  }
}

// ---------------- K5: yt row = irfft_4096(yf row)[0:2048]; grid 512 ----------------
__global__ __launch_bounds__(256) void ssm_k5(const float2* __restrict__ yf,
                                              float* __restrict__ yt, int dv) {
  __shared__ float2 b0[FFT_BUF];
  __shared__ float2 b1[FFT_BUF];
  int tid = threadIdx.x;
  int b = blockIdx.x >> 6, i = blockIdx.x & 63;
  const float2* src = yf + (size_t)(b*HD + i) * NF;
  float2* dst = (float2*)(yt + (((size_t)(dv*NB + b))*HD + i) * LSEQ);
  for (int k = tid; k < 2048; k += 256) {
    float2 Xk = src[k];
    float2 Xm = src[2048 - k];
    float Ex = (Xk.x + Xm.x)*0.5f, Ey = (Xk.y - Xm.y)*0.5f;
    float Dx = Xk.x - Xm.x,        Dy = Xk.y + Xm.y;
    float s, c;
    __sincosf(6.28318530717958647f * (float)k * (1.0f/4096.0f), &s, &c);
    float Ox = 0.5f*(Dx*c - Dy*s);
    float Oy = 0.5f*(Dx*s + Dy*c);
    b0[SL(k)] = make_float2(Ex - Oy, Ey + Ox);
  }
  r8_stage<1, 1>(b0, b1);
  r8_stage<1, 8>(b1, b0);
  r8_stage<1, 64>(b0, b1);
  r4f_gw_f32h(b1, dst);         // final r4, t<1024 only, scaled direct write
}

// ---------------- T2: yt[div][b][i][t] -> out[b][t][i*8+div] ----------------
__global__ __launch_bounds__(256) void ssm_t2(const float* __restrict__ yt, float* __restrict__ out) {
  __shared__ float s[512][17];
  int b  = blockIdx.x >> 7;
  int t0 = (blockIdx.x & 127) << 4;
  int tid = threadIdx.x;
  for (int q = tid; q < 512*16; q += 256) {
    int d = q >> 4, tt = q & 15;
    int dvv = d & 7, i = d >> 3;
    s[d][tt] = yt[(((size_t)(dvv*NB + b))*HD + i)*LSEQ + t0 + tt];
  }
  __syncthreads();
  for (int q = tid; q < 512*16; q += 256) {
    int tt = q >> 9, d = q & 511;
    out[((size_t)b*LSEQ + t0 + tt)*512 + d] = s[d][tt];
  }
}

// ---------------- host ----------------
extern "C" void kernel_launch(void* const* d_in, const int* in_sizes, int n_in,
                              void* d_out, int out_size, void* d_ws, size_t ws_size,
                              hipStream_t stream) {
  const float* u    = (const float*)d_in[0];
  const float* Lre  = (const float*)d_in[1];
  const float* Lim  = (const float*)d_in[2];
  const float* Pre  = (const float*)d_in[3];
  const float* Pim  = (const float*)d_in[4];
  const float* Bre  = (const float*)d_in[5];
  const float* Bim  = (const float*)d_in[6];
  const float* Cre  = (const float*)d_in[7];
  const float* Cim  = (const float*)d_in[8];
  const float* step = (const float*)d_in[9];
  float* out = (float*)d_out;

  char* w = (char*)d_ws;
  size_t off = 0;
  auto carve = [&](size_t bytes) -> void* {
    void* p = (void*)(w + off);
    off += (bytes + 255) & ~(size_t)255;
    return p;
  };
  float2*   cpx  = (float2*)carve((size_t)NDIV*LSEQ*sizeof(float2));          // 0.13 MB
  float*    ut   = (float*) carve((size_t)NDIV*NB*HD*LSEQ*sizeof(float));     // 33.55 MB (later = yt)
  unsigned* big  = (unsigned*)carve((size_t)4096*NFP*sizeof(unsigned) + 256); // 33.62 MB (bf16x2, padded rows + tail)
  float2*   yf   = (float2*)carve((size_t)512*NF*sizeof(float2));             // 8.39 MB (per div)
  float2*   CT   = (float2*)carve((size_t)NDIV*NM*HD*sizeof(float2));         // 256 KB
  float2*   BT   = (float2*)carve((size_t)NDIV*NM*HD*sizeof(float2));         // 256 KB
  float2*   PT   = (float2*)carve((size_t)NDIV*NM*sizeof(float2));            // 4 KB
  unsigned short* ATr  = (unsigned short*)carve((size_t)NDIV*ATROWS*64*2);    // 4.33 MB
  unsigned short* ATi  = (unsigned short*)carve((size_t)NDIV*ATROWS*64*2);    // 4.33 MB
  unsigned short* ATin = (unsigned short*)carve((size_t)NDIV*ATROWS*64*2);    // 4.33 MB
  unsigned short* RBr  = (unsigned short*)carve((size_t)NDIV*8*LSEQ*8*2);     // 2.10 MB
  unsigned short* RBi  = (unsigned short*)carve((size_t)NDIV*8*LSEQ*8*2);     // 2.10 MB
  float2*   A1h  = (float2*)carve((size_t)NDIV*64*LSEQ*sizeof(float2));       // 8.39 MB
  float2*   K10h = (float2*)carve((size_t)NDIV*LSEQ*64*sizeof(float2));       // 8.39 MB
  size_t off_m = off;
  // prefer all-div ud (33.6 MB bf16); fall back to per-div (4.2 MB) if ws too small
  unsigned* ud_full = (unsigned*)carve((size_t)NDIV*512*NF*sizeof(unsigned));
  bool full = (ws_size >= off);
  unsigned* ud = ud_full;
  if (!full) {
    off = off_m;
    ud = (unsigned*)carve((size_t)512*NF*sizeof(unsigned));
    if (ws_size < off) return;   // insufficient scratch -> clean failure
  }
  (void)in_sizes; (void)n_in; (void)out_size;

  ssm_kt<<<128, 256, 0, stream>>>(Cre, Cim, Bre, Bim, Pre, Pim, CT, BT, PT);
  ssm_k0a<<<256, 256, 0, stream>>>(Lre, Lim, Pre, Pim, step, RBr, RBi, cpx);
  ssm_km<<<dim3(65, 8), 256, 0, stream>>>(CT, BT, PT, ATr, ATi, ATin);
  ssm_ku<<<1024, 256, 0, stream>>>(u, ut);
  ssm_g1<<<dim3(2, 32, 8), 256, 0, stream>>>(ATr, ATi, ATin, RBr, RBi, cpx, A1h, K10h);
  if (full) ssm_k3<<<4096, 256, 0, stream>>>(ut, ud_full, 0);
  for (int dv = 0; dv < NDIV; ++dv) {
    if (!full) ssm_k3<<<512, 256, 0, stream>>>(ut, ud, dv*512);
    const unsigned* udp = full ? (ud_full + (size_t)dv*512*NF) : ud;
    ssm_g2<<<dim3(64, 32), 256, 0, stream>>>(ATr, ATi, ATin, RBr, RBi, A1h, K10h, big, dv);
    ssm_k2<<<4096, 256, 0, stream>>>(big);
    ssm_k4<<<dim3(257, 4), 256, 0, stream>>>(big, udp, yf);
    ssm_k5<<<512, 256, 0, stream>>>(yf, ut, dv);
  }
  ssm_t2<<<1024, 256, 0, stream>>>(ut, out);
}